// Round 3
// baseline (118.656 us; speedup 1.0000x reference)
//
#include <hip/hip_runtime.h>
#include <math.h>

#define HH 128
#define WW 128
#define NG 2048
#define DIMV 768
#define PIX (HH * WW)
#define A_MIN (1.0f / 255.0f)
#define TW 32             // tile width  (full 128B cachelines per channel row)
#define TH 2              // tile height
#define NT 512            // threads per block (8 waves)
#define NWV 8
#define CH 256            // survivor chunk size held in LDS
#define TWO_PI 6.28318530717958647692f

// ---------------------------------------------------------------------------
// Single fused kernel, one 32x2 pixel tile per block (256 blocks = 1/CU).
//  Phase W: stage w_up/b_up into LDS (12 KB) — overlaps with cull.
//  Phase B: cull all 2048 gaussians vs tile rect with REGISTER-ONLY lite
//           params (2 exp + 1 log, no trig). Exact-conservative bound:
//           alpha>=1/255 requires sigma <= ln(255*op); sigma >= |d|^2/(2*lmax);
//           lmax <= trace = s0^2+s1^2 (rotation-invariant -> no sin/cos).
//  Phase P: full conic/color ONLY for survivors (~45/tile), into 10 KB LDS.
//  Phase C: 8-way wave split over survivors, 1 pixel/lane, LDS broadcast.
//  Phase D: cross-wave reduce, clip -> 64-pixel tile rgb in LDS.
//  Phase E: expand to 768 channels, store directly. KEY vs round-1 fusion:
//           tile width 32 => each 16-lane group writes one FULL 128B-aligned
//           cacheline per channel row; no line shared across blocks (round-1's
//           16-wide tile split every line between two blocks => HBM merge).
// ---------------------------------------------------------------------------
__global__ __launch_bounds__(NT) void fused_kernel(
    const float* __restrict__ xyz, const float* __restrict__ scaling,
    const float* __restrict__ rotation, const float* __restrict__ features,
    const float* __restrict__ opacity, const float* __restrict__ w_up,
    const float* __restrict__ b_up, float* __restrict__ out)
{
    __shared__ int s_cnt;
    __shared__ int s_idx[NG];
    __shared__ float4 cA[CH];                 // (A/2, B, C/2, op)
    __shared__ float4 cB[CH];                 // (gx, gy, f0, f1)
    __shared__ float2 cC[CH];                 // (f2, -)
    __shared__ float s_red[NWV * 64 * 3];
    __shared__ __align__(16) float s_r[64];
    __shared__ __align__(16) float s_g[64];
    __shared__ __align__(16) float s_b[64];
    __shared__ float4 s_w[DIMV];              // (w0, w1, w2, bias) per channel

    int tid = threadIdx.x;
    int bx = blockIdx.x & 3, by = blockIdx.x >> 2;
    int px0 = bx * TW, py0 = by * TH;

    if (tid == 0) s_cnt = 0;

    // ---- Phase W: stage projection weights (independent loads, overlap cull)
    for (int d = tid; d < DIMV; d += NT)
        s_w[d] = make_float4(w_up[3 * d + 0], w_up[3 * d + 1],
                             w_up[3 * d + 2], b_up[d]);
    __syncthreads();

    // ---- Phase B: cull with register-only lite params (no trig)
    {
        float x0 = px0 + 0.5f, x1 = px0 + TW - 0.5f;
        float y0 = py0 + 0.5f, y1 = py0 + TH - 0.5f;
        #pragma unroll
        for (int g0 = 0; g0 < NG; g0 += NT) {
            int g = g0 + tid;
            float2 xz = ((const float2*)xyz)[g];
            float e2x = __expf(2.0f * xz.x);
            float e2y = 2.0f * __expf(2.0f * xz.y);
            float gx = (e2x / (e2x + 1.0f)) * (float)WW;   // 0.5*(tanh+1)*W
            float gy = (e2y / (e2y + 2.0f)) * (float)HH;
            float2 sc = ((const float2*)scaling)[g];
            float s0 = fabsf(sc.x + 0.5f);
            float s1 = fabsf(sc.y + 0.5f);
            float trc = s0 * s0 + s1 * s1;                 // >= lmax of cov
            float L = __logf(255.0f * opacity[g]);
            float r2 = (L > 0.0f) ? 2.0f * L * trc * 1.0002f + 1e-3f : -1.0f;
            float ddx = fmaxf(fmaxf(x0 - gx, gx - x1), 0.0f);
            float ddy = fmaxf(fmaxf(y0 - gy, gy - y1), 0.0f);
            if (ddx * ddx + ddy * ddy <= r2) {
                int pos = atomicAdd(&s_cnt, 1);
                s_idx[pos] = g;
            }
        }
    }
    __syncthreads();
    int cnt = s_cnt;

    int lane = tid & 63, wv = tid >> 6;
    float pxf = px0 + (lane & 31) + 0.5f;      // 32x2 lane -> pixel map
    float pyf = py0 + (lane >> 5) + 0.5f;
    float ar = 0.0f, ag = 0.0f, ab = 0.0f;

    // ---- survivors only: full params into LDS chunk, then accumulate
    for (int ck = 0; ck < cnt; ck += CH) {
        int csz = min(CH, cnt - ck);
        for (int j = tid; j < csz; j += NT) {
            int g = s_idx[ck + j];
            float2 xz = ((const float2*)xyz)[g];
            float e2x = __expf(2.0f * xz.x);
            float e2y = 2.0f * __expf(2.0f * xz.y);
            float gx = (e2x / (e2x + 1.0f)) * (float)WW;
            float gy = (e2y / (e2y + 2.0f)) * (float)HH;
            float2 sc = ((const float2*)scaling)[g];
            float s0 = fabsf(sc.x + 0.5f);
            float s1 = fabsf(sc.y + 0.5f);
            float th = TWO_PI / (1.0f + __expf(-rotation[g]));
            float sn = __sinf(th), cs = __cosf(th);
            float a = cs * s0, b = -sn * s1, d = sn * s0, e = cs * s1;
            float cxx = a * a + b * b;
            float cxy = a * d + b * e;
            float cyy = d * d + e * e;
            float inv = 1.0f / (cxx * cyy - cxy * cxy);  // det >= 1/16
            float op = opacity[g];
            cA[j] = make_float4(0.5f * cyy * inv, -cxy * inv, 0.5f * cxx * inv, op);
            cB[j] = make_float4(gx, gy, features[3 * g + 0], features[3 * g + 1]);
            cC[j] = make_float2(features[3 * g + 2], 0.0f);
        }
        __syncthreads();
        for (int k = wv; k < csz; k += NWV) {   // k wave-uniform -> broadcast
            float4 a0 = cA[k];
            float4 a1 = cB[k];
            float2 a2 = cC[k];
            float dx = a1.x - pxf, dy = a1.y - pyf;
            float sig = fmaf(a0.y * dx, dy, fmaf(a0.x * dx, dx, a0.z * dy * dy));
            float al = fminf(0.999f, a0.w * __expf(-sig));
            al = (sig < 0.0f || al < A_MIN) ? 0.0f : al;
            ar = fmaf(al, a1.z, ar);
            ag = fmaf(al, a1.w, ag);
            ab = fmaf(al, a2.x, ab);
        }
        __syncthreads();   // protect chunk before overwrite
    }

    // ---- Phase D: reduce across waves, clip -> tile rgb (pixel = row*32+col)
    s_red[(wv * 64 + lane) * 3 + 0] = ar;
    s_red[(wv * 64 + lane) * 3 + 1] = ag;
    s_red[(wv * 64 + lane) * 3 + 2] = ab;
    __syncthreads();
    if (tid < 64) {
        float sr = 0.0f, sg = 0.0f, sb = 0.0f;
        #pragma unroll
        for (int w = 0; w < NWV; ++w) {
            sr += s_red[(w * 64 + tid) * 3 + 0];
            sg += s_red[(w * 64 + tid) * 3 + 1];
            sb += s_red[(w * 64 + tid) * 3 + 2];
        }
        s_r[tid] = fminf(1.0f, fmaxf(0.0f, sr));
        s_g[tid] = fminf(1.0f, fmaxf(0.0f, sg));
        s_b[tid] = fminf(1.0f, fmaxf(0.0f, sb));
    }
    __syncthreads();

    // ---- Phase E: expand to 768 channels, store full cachelines.
    // q = pixel quad (row = q>>3, 4-px col group c4 = q&7), dbase = channel base.
    // Lanes 0..15 share a channel and cover one full 128B row line.
    int q = tid & 15, dbase = tid >> 4;          // dbase in [0,32)
    int row = q >> 3, c4 = q & 7;
    float4 r4 = *(const float4*)&s_r[row * 32 + c4 * 4];
    float4 g4 = *(const float4*)&s_g[row * 32 + c4 * 4];
    float4 b4 = *(const float4*)&s_b[row * 32 + c4 * 4];
    size_t pofs = (size_t)(py0 + row) * WW + px0 + c4 * 4;
    #pragma unroll 4
    for (int i = 0; i < DIMV / 32; ++i) {        // 24 iterations
        int d = dbase + (i << 5);
        float4 w = s_w[d];
        float4 v;
        v.x = fmaf(w.x, r4.x, fmaf(w.y, g4.x, fmaf(w.z, b4.x, w.w)));
        v.y = fmaf(w.x, r4.y, fmaf(w.y, g4.y, fmaf(w.z, b4.y, w.w)));
        v.z = fmaf(w.x, r4.z, fmaf(w.y, g4.z, fmaf(w.z, b4.z, w.w)));
        v.w = fmaf(w.x, r4.w, fmaf(w.y, g4.w, fmaf(w.z, b4.w, w.w)));
        *(float4*)(out + (size_t)d * PIX + pofs) = v;
    }
}

extern "C" void kernel_launch(void* const* d_in, const int* in_sizes, int n_in,
                              void* d_out, int out_size, void* d_ws, size_t ws_size,
                              hipStream_t stream)
{
    // setup_inputs order: x(unused), xyz, scaling, rotation, features, opacity, w_up, b_up
    const float* xyz      = (const float*)d_in[1];
    const float* scaling  = (const float*)d_in[2];
    const float* rotation = (const float*)d_in[3];
    const float* features = (const float*)d_in[4];
    const float* opacity  = (const float*)d_in[5];
    const float* w_up     = (const float*)d_in[6];
    const float* b_up     = (const float*)d_in[7];
    (void)d_ws; (void)ws_size;

    fused_kernel<<<256, NT, 0, stream>>>(xyz, scaling, rotation, features,
                                         opacity, w_up, b_up, (float*)d_out);
}

// Round 5
// 109.555 us; speedup vs baseline: 1.0831x; 1.0831x over previous
//
#include <hip/hip_runtime.h>
#include <math.h>

#define HH 128
#define WW 128
#define NG 2048
#define DIMV 768
#define PIX (HH * WW)
#define A_MIN (1.0f / 255.0f)
#define TW 16
#define TH 4
#define NT 512            // raster threads per block (8 waves)
#define NWV 8
#define CH 256            // survivor chunk size held in LDS
#define TWO_PI 6.28318530717958647692f

typedef float v4f __attribute__((ext_vector_type(4)));  // native vec for NT stores

// fast reciprocal: v_rcp_f32 (~2^-22 rel err; inputs here are well-conditioned)
__device__ __forceinline__ float frcp(float x) { return __builtin_amdgcn_rcpf(x); }

// ---------------------------------------------------------------------------
// K1 (raster): one 16x4 pixel tile per block (256 blocks, 512 threads).
//  Phase B: cull all 2048 gaussians vs tile rect using REGISTER-ONLY lite
//           params (gx,gy via 2 exp; r2 via log — no trig, no LDS tables).
//           Exact-conservative bound: alpha>=1/255 requires
//           sigma <= ln(255*op); sigma >= |d|^2/(2*lmax); lmax <= trace
//           = s0^2+s1^2 (rotation-invariant -> no sin/cos to cull).
//  Phase P: full conic/color ONLY for survivors (~45/tile vs 2048),
//           chunk-compacted into 10 KB of LDS.
//  Phase C: 8-way wave split over survivors, 1 pixel/lane, LDS broadcast.
//  Phase D: cross-wave reduce, clip, store img planes as float4 (48 stores).
// ---------------------------------------------------------------------------
__global__ __launch_bounds__(NT) void raster_kernel(
    const float* __restrict__ xyz, const float* __restrict__ scaling,
    const float* __restrict__ rotation, const float* __restrict__ features,
    const float* __restrict__ opacity, float* __restrict__ img)
{
    __shared__ int s_cnt;
    __shared__ int s_idx[NG];
    __shared__ float4 cA[CH];                 // (A/2, B, C/2, op)
    __shared__ float4 cB[CH];                 // (gx, gy, f0, f1)
    __shared__ float2 cC[CH];                 // (f2, -)
    __shared__ float s_red[NWV * 64 * 3];
    __shared__ __align__(16) float s_out[3 * 64];   // plane-major tile rgb

    int tid = threadIdx.x;
    int bx = blockIdx.x & 7, by = blockIdx.x >> 3;
    int px0 = bx * TW, py0 = by * TH;

    if (tid == 0) s_cnt = 0;
    __syncthreads();

    // ---- Phase B: cull with register-only lite params (no trig)
    {
        float x0 = px0 + 0.5f, x1 = px0 + TW - 0.5f;
        float y0 = py0 + 0.5f, y1 = py0 + TH - 0.5f;
        #pragma unroll
        for (int g0 = 0; g0 < NG; g0 += NT) {
            int g = g0 + tid;
            float2 xz = ((const float2*)xyz)[g];
            float e2x = __expf(2.0f * xz.x);
            float e2y = 2.0f * __expf(2.0f * xz.y);
            float gx = e2x * frcp(e2x + 1.0f) * (float)WW;   // 0.5*(tanh+1)*W
            float gy = e2y * frcp(e2y + 2.0f) * (float)HH;
            float2 sc = ((const float2*)scaling)[g];
            float s0 = fabsf(sc.x + 0.5f);
            float s1 = fabsf(sc.y + 0.5f);
            float trc = s0 * s0 + s1 * s1;                 // >= lmax of cov
            float L = __logf(255.0f * opacity[g]);
            float r2 = (L > 0.0f) ? 2.0f * L * trc * 1.0002f + 1e-3f : -1.0f;
            float ddx = fmaxf(fmaxf(x0 - gx, gx - x1), 0.0f);
            float ddy = fmaxf(fmaxf(y0 - gy, gy - y1), 0.0f);
            if (ddx * ddx + ddy * ddy <= r2) {
                int pos = atomicAdd(&s_cnt, 1);
                s_idx[pos] = g;
            }
        }
    }
    __syncthreads();
    int cnt = s_cnt;

    int lane = tid & 63, wv = tid >> 6;
    float pxf = px0 + (lane & 15) + 0.5f;
    float pyf = py0 + (lane >> 4) + 0.5f;
    float ar = 0.0f, ag = 0.0f, ab = 0.0f;

    // ---- survivors only: full params into LDS chunk, then accumulate
    for (int ck = 0; ck < cnt; ck += CH) {
        int csz = min(CH, cnt - ck);
        for (int j = tid; j < csz; j += NT) {
            int g = s_idx[ck + j];
            float2 xz = ((const float2*)xyz)[g];
            float e2x = __expf(2.0f * xz.x);
            float e2y = 2.0f * __expf(2.0f * xz.y);
            float gx = e2x * frcp(e2x + 1.0f) * (float)WW;
            float gy = e2y * frcp(e2y + 2.0f) * (float)HH;
            float2 sc = ((const float2*)scaling)[g];
            float s0 = fabsf(sc.x + 0.5f);
            float s1 = fabsf(sc.y + 0.5f);
            float th = TWO_PI * frcp(1.0f + __expf(-rotation[g]));
            float sn = __sinf(th), cs = __cosf(th);
            float a = cs * s0, b = -sn * s1, d = sn * s0, e = cs * s1;
            float cxx = a * a + b * b;
            float cxy = a * d + b * e;
            float cyy = d * d + e * e;
            float inv = frcp(cxx * cyy - cxy * cxy);  // det >= 1/16
            float op = opacity[g];
            cA[j] = make_float4(0.5f * cyy * inv, -cxy * inv, 0.5f * cxx * inv, op);
            cB[j] = make_float4(gx, gy, features[3 * g + 0], features[3 * g + 1]);
            cC[j] = make_float2(features[3 * g + 2], 0.0f);
        }
        __syncthreads();
        for (int k = wv; k < csz; k += NWV) {   // k wave-uniform -> broadcast
            float4 a0 = cA[k];
            float4 a1 = cB[k];
            float2 a2 = cC[k];
            float dx = a1.x - pxf, dy = a1.y - pyf;
            float sig = fmaf(a0.y * dx, dy, fmaf(a0.x * dx, dx, a0.z * dy * dy));
            float al = fminf(0.999f, a0.w * __expf(-sig));
            al = (sig < 0.0f || al < A_MIN) ? 0.0f : al;
            ar = fmaf(al, a1.z, ar);
            ag = fmaf(al, a1.w, ag);
            ab = fmaf(al, a2.x, ab);
        }
        __syncthreads();   // protect chunk before overwrite
    }

    // ---- Phase D: reduce across waves, clip -> plane-major LDS
    s_red[(wv * 64 + lane) * 3 + 0] = ar;
    s_red[(wv * 64 + lane) * 3 + 1] = ag;
    s_red[(wv * 64 + lane) * 3 + 2] = ab;
    __syncthreads();
    if (tid < 64) {
        float sr = 0.0f, sg = 0.0f, sb = 0.0f;
        #pragma unroll
        for (int w = 0; w < NWV; ++w) {
            sr += s_red[(w * 64 + tid) * 3 + 0];
            sg += s_red[(w * 64 + tid) * 3 + 1];
            sb += s_red[(w * 64 + tid) * 3 + 2];
        }
        s_out[tid]       = fminf(1.0f, fmaxf(0.0f, sr));
        s_out[64 + tid]  = fminf(1.0f, fmaxf(0.0f, sg));
        s_out[128 + tid] = fminf(1.0f, fmaxf(0.0f, sb));
    }
    __syncthreads();

    // ---- vectorized store: 48 float4 = 3 planes x 4 rows x 64B
    if (tid < 48) {
        int plane = tid >> 4, q = tid & 15;
        int row = q >> 2, c4 = q & 3;
        float4 v = *(const float4*)&s_out[plane * 64 + row * 16 + c4 * 4];
        *(float4*)(img + (size_t)plane * PIX + (py0 + row) * WW + px0 + c4 * 4) = v;
    }
}

// ---------------------------------------------------------------------------
// K2: projection to 768 channels. 3072 blocks: blockIdx = grp*16+seg,
// grp -> 4 consecutive channels, seg -> 1024-pixel span. Pure write-bound:
// 3x float4 L2-resident img reads, 16 FMA, 4x float4 coalesced NONTEMPORAL
// stores (no L2 write-allocate thrash; 50.3 MB streamed straight out).
// ---------------------------------------------------------------------------
__global__ __launch_bounds__(256) void project_kernel(
    const float* __restrict__ img, const float* __restrict__ w_up,
    const float* __restrict__ b_up, float* __restrict__ out)
{
    int grp = blockIdx.x >> 4;
    int seg = blockIdx.x & 15;
    int p = seg * 1024 + threadIdx.x * 4;
    float4 r = *(const float4*)(img + p);
    float4 g = *(const float4*)(img + PIX + p);
    float4 b = *(const float4*)(img + 2 * PIX + p);
    int d0 = grp * 4;
    #pragma unroll
    for (int i = 0; i < 4; ++i) {
        int d = d0 + i;
        float w0 = w_up[3 * d + 0], w1 = w_up[3 * d + 1], w2 = w_up[3 * d + 2];
        float bb = b_up[d];
        v4f v;
        v.x = fmaf(w0, r.x, fmaf(w1, g.x, fmaf(w2, b.x, bb)));
        v.y = fmaf(w0, r.y, fmaf(w1, g.y, fmaf(w2, b.y, bb)));
        v.z = fmaf(w0, r.z, fmaf(w1, g.z, fmaf(w2, b.z, bb)));
        v.w = fmaf(w0, r.w, fmaf(w1, g.w, fmaf(w2, b.w, bb)));
        __builtin_nontemporal_store(v, (v4f*)(out + (size_t)d * PIX + p));
    }
}

extern "C" void kernel_launch(void* const* d_in, const int* in_sizes, int n_in,
                              void* d_out, int out_size, void* d_ws, size_t ws_size,
                              hipStream_t stream)
{
    // setup_inputs order: x(unused), xyz, scaling, rotation, features, opacity, w_up, b_up
    const float* xyz      = (const float*)d_in[1];
    const float* scaling  = (const float*)d_in[2];
    const float* rotation = (const float*)d_in[3];
    const float* features = (const float*)d_in[4];
    const float* opacity  = (const float*)d_in[5];
    const float* w_up     = (const float*)d_in[6];
    const float* b_up     = (const float*)d_in[7];
    float* out = (float*)d_out;
    float* img = (float*)d_ws;   // 3 planes of PIX floats (192 KB, L2-resident)

    raster_kernel<<<256, NT, 0, stream>>>(xyz, scaling, rotation, features,
                                          opacity, img);
    project_kernel<<<(DIMV / 4) * 16, 256, 0, stream>>>(img, w_up, b_up, out);
}